// Round 4
// baseline (31224.826 us; speedup 1.0000x reference)
//
#include <hip/hip_runtime.h>
#include <math.h>

#define BB 256   // batch
#define TT 128   // time steps
#define DD 256   // input dim
#define UU 512   // units
#define NBLK 256 // persistent blocks (1 per CU)

// W1: K=768 (512 h-rows + 256 x-rows) x 4096 cols (u*8+g), g: 0=z 1=r 2=hx 3=hr 4=l 5=l2
#define W1_K 768
#define W1_N 4096
#define W1_SIZE (W1_K * W1_N)          // 3,145,728
#define W2_SIZE (UU * 2048)            // 1,048,576 (cols u*4+g, g:0=z 1=r 2=h 3=pad)

__device__ __forceinline__ float hsig(float x) {
    return fminf(fmaxf(0.2f * x + 0.5f, 0.0f), 1.0f);
}

// ---------------------------------------------------------------------------
// One-time pack: gate-interleaved weights + combined biases + h init + barrier
// flag zeroing (ws is poisoned 0xAA before every call — all init lives here).
// ---------------------------------------------------------------------------
__global__ __launch_bounds__(256) void pack_all(
    const float* __restrict__ kernel,   // (256,2560)
    const float* __restrict__ rk,       // (512,2048)
    const float* __restrict__ tk,       // (2,512,1536)
    const float* __restrict__ bias,     // (2,2560)
    const float* __restrict__ tb,       // (2,1536)
    const float* __restrict__ h0,       // (256,512)
    float* __restrict__ W1, float* __restrict__ W2, float* __restrict__ W3,
    float* __restrict__ b1, float* __restrict__ b2, float* __restrict__ b3,
    float* __restrict__ h, unsigned* __restrict__ flags)
{
    int idx = blockIdx.x * 256 + threadIdx.x;
    if (idx < W1_SIZE) {
        int k = idx >> 12, c = idx & 4095, u = c >> 3, g = c & 7;
        float v = 0.f;
        if (k < UU) {
            const float* r = rk + (size_t)k * 2048;
            if (g == 0) v = r[u];
            else if (g == 1) v = r[512 + u];
            else if (g == 3) v = r[1024 + u];
            else if (g == 4) v = r[1536 + u];
        } else {
            const float* kr = kernel + (size_t)(k - UU) * 2560;
            if (g == 0) v = kr[u];
            else if (g == 1) v = kr[512 + u];
            else if (g == 2) v = kr[1024 + u];
            else if (g == 4) v = kr[1536 + u];
            else if (g == 5) v = kr[2048 + u];
        }
        W1[idx] = v;
        return;
    }
    idx -= W1_SIZE;
    if (idx < W2_SIZE) {
        int k = idx >> 11, c = idx & 2047, u = c >> 2, g = c & 3;
        W2[idx] = (g < 3) ? tk[(size_t)k * 1536 + g * 512 + u] : 0.f;
        return;
    }
    idx -= W2_SIZE;
    if (idx < W2_SIZE) {
        int k = idx >> 11, c = idx & 2047, u = c >> 2, g = c & 3;
        W3[idx] = (g < 3) ? tk[(size_t)(512 + k) * 1536 + g * 512 + u] : 0.f;
        return;
    }
    idx -= W2_SIZE;
    if (idx < 4096) {
        int u = idx >> 3, g = idx & 7;
        float v = 0.f;
        if (g == 0) v = bias[u] + bias[2560 + u];
        else if (g == 1) v = bias[512 + u] + bias[2560 + 512 + u];
        else if (g == 2) v = bias[1024 + u];
        else if (g == 3) v = bias[2560 + 1024 + u];
        else if (g == 4) v = bias[1536 + u] + bias[2560 + 1536 + u];
        else if (g == 5) v = bias[2048 + u];
        b1[idx] = v;
        return;
    }
    idx -= 4096;
    if (idx < 2048) {
        int u = idx >> 2, g = idx & 3;
        b2[idx] = (g < 3) ? tb[g * 512 + u] : 0.f;
        return;
    }
    idx -= 2048;
    if (idx < 2048) {
        int u = idx >> 2, g = idx & 3;
        b3[idx] = (g < 3) ? tb[1536 + g * 512 + u] : 0.f;
        return;
    }
    idx -= 2048;
    if (idx < BB * UU) {   // h init
        h[idx] = h0[idx];
        return;
    }
    idx -= BB * UU;
    if (idx < 64) {        // barrier flags: [0]=counter [1]=gen [2]=broken
        flags[idx] = 0u;
        return;
    }
}

// ---------------------------------------------------------------------------
// Grid barrier: sense-reversing, agent-scope atomics. __threadfence() emits a
// cache-wide L2 writeback on gfx950 so one lane's fence covers the block's
// completed stores (__syncthreads drains each lane's vmcnt first). Bounded
// spin -> 'broken' flag instead of a harness-killing deadlock.
// ---------------------------------------------------------------------------
__device__ __forceinline__ void gbar(unsigned* flags) {
    __syncthreads();
    if (threadIdx.x == 0) {
        if (__hip_atomic_load(&flags[2], __ATOMIC_RELAXED,
                              __HIP_MEMORY_SCOPE_AGENT) == 0u) {
            __threadfence();
            unsigned my = __hip_atomic_load(&flags[1], __ATOMIC_RELAXED,
                                            __HIP_MEMORY_SCOPE_AGENT);
            unsigned prev = __hip_atomic_fetch_add(&flags[0], 1u,
                                                   __ATOMIC_ACQ_REL,
                                                   __HIP_MEMORY_SCOPE_AGENT);
            if (prev == NBLK - 1) {
                __hip_atomic_store(&flags[0], 0u, __ATOMIC_RELAXED,
                                   __HIP_MEMORY_SCOPE_AGENT);
                __hip_atomic_store(&flags[1], my + 1u, __ATOMIC_RELEASE,
                                   __HIP_MEMORY_SCOPE_AGENT);
            } else {
                long spins = 0;
                while (__hip_atomic_load(&flags[1], __ATOMIC_ACQUIRE,
                                         __HIP_MEMORY_SCOPE_AGENT) == my) {
                    if (++spins > 30000000L) {
                        __hip_atomic_store(&flags[2], 1u, __ATOMIC_RELEASE,
                                           __HIP_MEMORY_SCOPE_AGENT);
                        break;
                    }
                }
            }
        }
    }
    __syncthreads();
}

// ---------------------------------------------------------------------------
// Persistent scan: 256 blocks (1D; ub = bid&31 u-slab, bm = (bid>>5)*32 rows),
// 256 threads. 3 phases per step, grid barrier between.
// ---------------------------------------------------------------------------
__global__ __launch_bounds__(256) void scan_kernel(
    const float* __restrict__ x,
    const float* __restrict__ W1, const float* __restrict__ b1,
    const float* __restrict__ W2, const float* __restrict__ b2,
    const float* __restrict__ W3, const float* __restrict__ b3,
    float* __restrict__ h, float* __restrict__ h1a, float* __restrict__ h1b,
    float* __restrict__ lbuf, float* __restrict__ tl2,
    float* __restrict__ out, unsigned* __restrict__ flags)
{
    __shared__ float As[16][33];
    __shared__ float WsF[16 * 132];

    const int bid = blockIdx.x;
    const int ub  = bid & 31;            // u-slab 0..31 (same-ub blocks: same XCD under %8)
    const int bm  = (bid >> 5) * 32;     // row base
    const int tid = threadIdx.x;
    const int tx  = tid & 15;
    const int ty  = tid >> 4;
    const int ar  = tid >> 3;
    const int ac  = (tid & 7) * 2;
    const int wr  = tid >> 4;
    const int u   = ub * 16 + tx;
    const int row0 = bm + ty * 2;

    const float bz  = b1[u * 8 + 0], br  = b1[u * 8 + 1];
    const float bhx = b1[u * 8 + 2], bhr = b1[u * 8 + 3];
    const float bl  = b1[u * 8 + 4], bl2 = b1[u * 8 + 5];
    const float b2z = b2[u * 4 + 0], b2r = b2[u * 4 + 1], b2h = b2[u * 4 + 2];
    const float b3z = b3[u * 4 + 0], b3r = b3[u * 4 + 1], b3h = b3[u * 4 + 2];

    for (int t = 0; t < TT; ++t) {
        // ---------------- phase 1: gates (K = 512 h + 256 x) ----------------
        {
            const int wc = (tid & 15) * 8;
            float az[2] = {}, arr_[2] = {}, ahx[2] = {}, ahr[2] = {},
                  al[2] = {}, al2[2] = {};
            for (int k0 = 0; k0 < W1_K; k0 += 16) {
                float2 av;
                if (k0 < UU)
                    av = *(const float2*)(h + (size_t)(bm + ar) * UU + k0 + ac);
                else
                    av = *(const float2*)(x + ((size_t)(bm + ar) * TT + t) * DD
                                          + (k0 - UU) + ac);
                const float* wp = W1 + (size_t)(k0 + wr) * W1_N + ub * 128 + wc;
                float4 w0 = *(const float4*)(wp);
                float4 w1 = *(const float4*)(wp + 4);
                As[ac][ar] = av.x; As[ac + 1][ar] = av.y;
                *(float4*)&WsF[wr * 132 + wc]     = w0;
                *(float4*)&WsF[wr * 132 + wc + 4] = w1;
                __syncthreads();
#pragma unroll
                for (int kk = 0; kk < 16; ++kk) {
                    float a0 = As[kk][ty * 2];
                    float a1 = As[kk][ty * 2 + 1];
                    float4 wA = *(const float4*)&WsF[kk * 132 + tx * 8];
                    float2 wB = *(const float2*)&WsF[kk * 132 + tx * 8 + 4];
                    az[0]  += a0 * wA.x; arr_[0] += a0 * wA.y;
                    ahx[0] += a0 * wA.z; ahr[0] += a0 * wA.w;
                    al[0]  += a0 * wB.x; al2[0] += a0 * wB.y;
                    az[1]  += a1 * wA.x; arr_[1] += a1 * wA.y;
                    ahx[1] += a1 * wA.z; ahr[1] += a1 * wA.w;
                    al[1]  += a1 * wB.x; al2[1] += a1 * wB.y;
                }
                __syncthreads();
            }
#pragma unroll
            for (int i = 0; i < 2; ++i) {
                int row = row0 + i;
                float z  = hsig(az[i] + bz);
                float r  = hsig(arr_[i] + br);
                float hh = tanhf((ahx[i] + bhx) + r * (ahr[i] + bhr));
                float hold = h[(size_t)row * UU + u];
                h1a[(size_t)row * UU + u]  = z * hold + (1.0f - z) * hh;
                lbuf[(size_t)row * UU + u] = hsig(al[i] + bl);
                tl2[(size_t)row * UU + u]  = tanhf(al2[i] + bl2);
            }
        }
        gbar(flags);

        // ---------------- phase 2: transition 0 ----------------
        {
            const int wc = (tid & 15) * 4;
            float acz[2] = {}, acr[2] = {}, ach[2] = {};
            for (int k0 = 0; k0 < UU; k0 += 16) {
                float2 av = *(const float2*)(h1a + (size_t)(bm + ar) * UU + k0 + ac);
                float4 w = *(const float4*)(W2 + (size_t)(k0 + wr) * 2048
                                            + ub * 64 + wc);
                As[ac][ar] = av.x; As[ac + 1][ar] = av.y;
                *(float4*)&WsF[wr * 132 + wc] = w;
                __syncthreads();
#pragma unroll
                for (int kk = 0; kk < 16; ++kk) {
                    float a0 = As[kk][ty * 2];
                    float a1 = As[kk][ty * 2 + 1];
                    float4 w4 = *(const float4*)&WsF[kk * 132 + tx * 4];
                    acz[0] += a0 * w4.x; acr[0] += a0 * w4.y; ach[0] += a0 * w4.z;
                    acz[1] += a1 * w4.x; acr[1] += a1 * w4.y; ach[1] += a1 * w4.z;
                }
                __syncthreads();
            }
#pragma unroll
            for (int i = 0; i < 2; ++i) {
                int row = row0 + i;
                float zt = hsig(acz[i] + b2z);
                float rt = hsig(acr[i] + b2r);
                float ht = tanhf(rt * (ach[i] + b2h));
                float h1v = h1a[(size_t)row * UU + u];
                h1b[(size_t)row * UU + u] = zt * h1v + (1.0f - zt) * ht;
            }
        }
        gbar(flags);

        // ---------------- phase 3: transition 1 + output gate ----------------
        {
            const int wc = (tid & 15) * 4;
            float acz[2] = {}, acr[2] = {}, ach[2] = {};
            for (int k0 = 0; k0 < UU; k0 += 16) {
                float2 av = *(const float2*)(h1b + (size_t)(bm + ar) * UU + k0 + ac);
                float4 w = *(const float4*)(W3 + (size_t)(k0 + wr) * 2048
                                            + ub * 64 + wc);
                As[ac][ar] = av.x; As[ac + 1][ar] = av.y;
                *(float4*)&WsF[wr * 132 + wc] = w;
                __syncthreads();
#pragma unroll
                for (int kk = 0; kk < 16; ++kk) {
                    float a0 = As[kk][ty * 2];
                    float a1 = As[kk][ty * 2 + 1];
                    float4 w4 = *(const float4*)&WsF[kk * 132 + tx * 4];
                    acz[0] += a0 * w4.x; acr[0] += a0 * w4.y; ach[0] += a0 * w4.z;
                    acz[1] += a1 * w4.x; acr[1] += a1 * w4.y; ach[1] += a1 * w4.z;
                }
                __syncthreads();
            }
#pragma unroll
            for (int i = 0; i < 2; ++i) {
                int row = row0 + i;
                float zt = hsig(acz[i] + b3z);
                float rt = hsig(acr[i] + b3r);
                float ht = tanhf(rt * (ach[i] + b3h));
                float h1v = h1b[(size_t)row * UU + u];
                float h2  = zt * h1v + (1.0f - zt) * ht;
                float l   = lbuf[(size_t)row * UU + u];
                float ho  = l * h2 + (1.0f - l) * tl2[(size_t)row * UU + u];
                h[(size_t)row * UU + u] = ho;
                out[((size_t)row * TT + t) * UU + u] = ho;
            }
        }
        gbar(flags);
    }
}

extern "C" void kernel_launch(void* const* d_in, const int* in_sizes, int n_in,
                              void* d_out, int out_size, void* d_ws, size_t ws_size,
                              hipStream_t stream) {
    const float* x      = (const float*)d_in[0];
    const float* h0     = (const float*)d_in[1];
    const float* kernel = (const float*)d_in[2];
    const float* rk     = (const float*)d_in[3];
    const float* tk     = (const float*)d_in[4];
    const float* bias   = (const float*)d_in[5];
    const float* tb     = (const float*)d_in[6];
    float* out = (float*)d_out;
    float* ws  = (float*)d_ws;

    float* W1   = ws;                        // 3,145,728
    float* W2   = W1 + W1_SIZE;              // 1,048,576
    float* W3   = W2 + W2_SIZE;              // 1,048,576
    float* b1   = W3 + W2_SIZE;              // 4096
    float* b2   = b1 + 4096;                 // 2048
    float* b3   = b2 + 2048;                 // 2048
    float* h    = b3 + 2048;                 // 131072
    float* h1a  = h    + (size_t)BB * UU;
    float* h1b  = h1a  + (size_t)BB * UU;
    float* lbuf = h1b  + (size_t)BB * UU;
    float* tl2  = lbuf + (size_t)BB * UU;
    unsigned* flags = (unsigned*)(tl2 + (size_t)BB * UU);

    int pack_elems = W1_SIZE + 2 * W2_SIZE + 4096 + 2048 + 2048 + BB * UU + 64;
    pack_all<<<dim3((pack_elems + 255) / 256), dim3(256), 0, stream>>>(
        kernel, rk, tk, bias, tb, h0, W1, W2, W3, b1, b2, b3, h, flags);

    void* args[] = {(void*)&x, (void*)&W1, (void*)&b1, (void*)&W2, (void*)&b2,
                    (void*)&W3, (void*)&b3, (void*)&h, (void*)&h1a, (void*)&h1b,
                    (void*)&lbuf, (void*)&tl2, (void*)&out, (void*)&flags};
    hipError_t err = hipLaunchCooperativeKernel((void*)scan_kernel, dim3(NBLK),
                                                dim3(256), args, 0, stream);
    if (err != hipSuccess) {
        (void)hipGetLastError();  // clear sticky error, fall back to plain launch
        scan_kernel<<<dim3(NBLK), dim3(256), 0, stream>>>(
            x, W1, b1, W2, b2, W3, b3, h, h1a, h1b, lbuf, tl2, out, flags);
    }
}

// Round 5
// 18674.164 us; speedup vs baseline: 1.6721x; 1.6721x over previous
//
#include <hip/hip_runtime.h>
#include <math.h>

#define BB 256
#define TT 128
#define DD 256
#define UU 512
#define NBLK 256

typedef unsigned short ushort_t;
typedef __attribute__((ext_vector_type(8))) short bf16x8;
typedef __attribute__((ext_vector_type(4))) float f32x4;
typedef __attribute__((ext_vector_type(4))) unsigned short us4;

#define W1T_E (12*32*96*72)   // 2,654,208  [kc][slab][col=g*16+n][k 72pad]
#define W2T_E (8*32*48*72)    //   884,736

__device__ __forceinline__ float hsig(float x){ return fminf(fmaxf(0.2f*x+0.5f,0.f),1.f); }
__device__ __forceinline__ ushort_t f2bf(float f){
    unsigned u = __float_as_uint(f);
    u = u + 0x7fffu + ((u>>16)&1u);        // RNE
    return (ushort_t)(u>>16);
}
__device__ __forceinline__ float bf2f(ushort_t h){ return __uint_as_float(((unsigned)h)<<16); }

__device__ __forceinline__ f32x4 mfma3(bf16x8 ah, bf16x8 al, bf16x8 bh, bf16x8 bl, f32x4 c){
    c = __builtin_amdgcn_mfma_f32_16x16x32_bf16(ah, bh, c, 0, 0, 0);
    c = __builtin_amdgcn_mfma_f32_16x16x32_bf16(al, bh, c, 0, 0, 0);
    c = __builtin_amdgcn_mfma_f32_16x16x32_bf16(ah, bl, c, 0, 0, 0);
    return c;
}

// ---------------------------------------------------------------------------
// One-time pack: bf16 hi/lo split weights, pre-transposed per 64-K chunk:
// layout [kc][slab][col][k72] so the LDS image is a straight linear copy and
// B-fragments come out as contiguous-K ds_read_b128 (2-way bank alias only).
// Gate order g: 0=z 1=r 2=hx 3=hr 4=l 5=l2. Also zeroes barrier flags.
// ---------------------------------------------------------------------------
__global__ __launch_bounds__(256) void pack_all(
    const float* __restrict__ kernel_, const float* __restrict__ rk,
    const float* __restrict__ tk,
    ushort_t* __restrict__ W1h, ushort_t* __restrict__ W1l,
    ushort_t* __restrict__ W2h, ushort_t* __restrict__ W2l,
    ushort_t* __restrict__ W3h, ushort_t* __restrict__ W3l,
    unsigned* __restrict__ flags)
{
    long idx = (long)blockIdx.x*256 + threadIdx.x;
    if (idx < W1T_E){
        int kk = (int)(idx % 72); long t1 = idx / 72;
        int col = (int)(t1 % 96); long t2 = t1 / 96;
        int s  = (int)(t2 % 32); int kc = (int)(t2 / 32);
        int g = col >> 4; int u = s*16 + (col & 15);
        int k = kc*64 + kk;
        float v = 0.f;
        if (kk < 64){
            if (k < UU){
                if (g==0)      v = rk[(size_t)k*2048 + u];
                else if (g==1) v = rk[(size_t)k*2048 + 512 + u];
                else if (g==3) v = rk[(size_t)k*2048 + 1024 + u];
                else if (g==4) v = rk[(size_t)k*2048 + 1536 + u];
            } else {
                int k2 = k - UU;
                if (g==0)      v = kernel_[(size_t)k2*2560 + u];
                else if (g==1) v = kernel_[(size_t)k2*2560 + 512 + u];
                else if (g==2) v = kernel_[(size_t)k2*2560 + 1024 + u];
                else if (g==4) v = kernel_[(size_t)k2*2560 + 1536 + u];
                else if (g==5) v = kernel_[(size_t)k2*2560 + 2048 + u];
            }
        }
        ushort_t hi = f2bf(v);
        W1h[idx] = hi; W1l[idx] = f2bf(v - bf2f(hi));
        return;
    }
    idx -= W1T_E;
    if (idx < 2L*W2T_E){
        int layer = (int)(idx / W2T_E);
        long j = idx % W2T_E;
        int kk = (int)(j % 72); long t1 = j / 72;
        int col = (int)(t1 % 48); long t2 = t1 / 48;
        int s = (int)(t2 % 32); int kc = (int)(t2 / 32);
        int g = col >> 4; int u = s*16 + (col & 15);
        int k = kc*64 + kk;
        float v = (kk < 64) ? tk[((size_t)layer*UU + k)*1536 + g*512 + u] : 0.f;
        ushort_t hi = f2bf(v);
        ushort_t* Wh_ = layer ? W3h : W2h;
        ushort_t* Wl_ = layer ? W3l : W2l;
        Wh_[j] = hi; Wl_[j] = f2bf(v - bf2f(hi));
        return;
    }
    idx -= 2L*W2T_E;
    if (idx < 1024) flags[idx] = 0u;
}

// ---------------------------------------------------------------------------
// Two-level grid barrier, cumulative counts (no reset races).
// flags: [g*32] g<8 group counters | [256] root | [512+g*32] release mirrors
//        | [960] broken. Group g = bid&7 (32 blocks each, XCD-affine).
// ---------------------------------------------------------------------------
__device__ __forceinline__ void gbar(unsigned* flags, int bid, int bno){
    __syncthreads();
    if (threadIdx.x == 0){
        unsigned grp = (unsigned)(bid & 7);
        __threadfence();
        if (__hip_atomic_load(&flags[960], __ATOMIC_RELAXED, __HIP_MEMORY_SCOPE_AGENT) == 0u){
            unsigned prev = __hip_atomic_fetch_add(&flags[grp*32], 1u,
                                __ATOMIC_ACQ_REL, __HIP_MEMORY_SCOPE_AGENT);
            if (prev == (unsigned)(bno*32 - 1)){
                unsigned pr = __hip_atomic_fetch_add(&flags[256], 1u,
                                __ATOMIC_ACQ_REL, __HIP_MEMORY_SCOPE_AGENT);
                if (pr == (unsigned)(bno*8 - 1)){
                    for (int g2 = 0; g2 < 8; ++g2)
                        __hip_atomic_store(&flags[512 + g2*32], (unsigned)bno,
                                __ATOMIC_RELEASE, __HIP_MEMORY_SCOPE_AGENT);
                }
            }
            long spins = 0;
            while (__hip_atomic_load(&flags[512 + grp*32], __ATOMIC_ACQUIRE,
                                     __HIP_MEMORY_SCOPE_AGENT) < (unsigned)bno){
                if (++spins > 20000000L){
                    __hip_atomic_store(&flags[960], 1u, __ATOMIC_RELEASE,
                                       __HIP_MEMORY_SCOPE_AGENT);
                    break;
                }
            }
        }
    }
    __syncthreads();
}

// ---------------------------------------------------------------------------
// Staging helpers
// ---------------------------------------------------------------------------
__device__ __forceinline__ void stage_w(const ushort_t* __restrict__ gh,
                                        const ushort_t* __restrict__ gl,
                                        ushort_t* lh, ushort_t* ll, int n16, int tid){
    const uint4* sh = (const uint4*)gh; const uint4* sl = (const uint4*)gl;
    uint4* dh = (uint4*)lh; uint4* dl = (uint4*)ll;
    for (int i = tid; i < n16; i += 256){ dh[i] = sh[i]; dl[i] = sl[i]; }
}

// A: 32 rows x 64 k, f32 source, split to bf16 hi/lo into [row][72]
__device__ __forceinline__ void stage_a(const float* __restrict__ A, int rowG,
                                        int kbase, ushort_t* ah, ushort_t* al, int tid){
#pragma unroll
    for (int it = 0; it < 2; ++it){
        int i = tid + it*256;
        int row = i >> 4; int kq = (i & 15) * 4;
        float4 v = *(const float4*)(A + (size_t)(rowG+row)*UU + kbase + kq);
        ushort_t h0_ = f2bf(v.x), h1_ = f2bf(v.y), h2_ = f2bf(v.z), h3_ = f2bf(v.w);
        us4 hv = {h0_, h1_, h2_, h3_};
        us4 lv = {f2bf(v.x - bf2f(h0_)), f2bf(v.y - bf2f(h1_)),
                  f2bf(v.z - bf2f(h2_)), f2bf(v.w - bf2f(h3_))};
        *(us4*)&ah[row*72 + kq] = hv;
        *(us4*)&al[row*72 + kq] = lv;
    }
}

// phase-1 A: k<512 from h-state, k>=512 from x[:,t,:]
__device__ __forceinline__ void stage_a1(const float* __restrict__ H,
                                         const float* __restrict__ x, int rowG,
                                         int kc, int t, ushort_t* ah, ushort_t* al, int tid){
#pragma unroll
    for (int it = 0; it < 2; ++it){
        int i = tid + it*256;
        int row = i >> 4; int kq = (i & 15) * 4;
        const float* src;
        if (kc < 8) src = H + (size_t)(rowG+row)*UU + kc*64 + kq;
        else        src = x + ((size_t)(rowG+row)*TT + t)*DD + (kc-8)*64 + kq;
        float4 v = *(const float4*)src;
        ushort_t h0_ = f2bf(v.x), h1_ = f2bf(v.y), h2_ = f2bf(v.z), h3_ = f2bf(v.w);
        us4 hv = {h0_, h1_, h2_, h3_};
        us4 lv = {f2bf(v.x - bf2f(h0_)), f2bf(v.y - bf2f(h1_)),
                  f2bf(v.z - bf2f(h2_)), f2bf(v.w - bf2f(h3_))};
        *(us4*)&ah[row*72 + kq] = hv;
        *(us4*)&al[row*72 + kq] = lv;
    }
}

// ---------------------------------------------------------------------------
// Persistent MFMA scan. 256 blocks = 8 row-blocks(32 rows) x 32 u-slabs(16 u).
// bid = rb*32 + s  ->  bid%8 == s%8: slab peers share an XCD (L2-resident W).
// Waves: phase1 wave w owns (rowtile w>>1, gates {0,1,2} or {3,4,5}).
// ---------------------------------------------------------------------------
__global__ __launch_bounds__(256) void scan_kernel(
    const float* __restrict__ x, const float* __restrict__ h0,
    const float* __restrict__ bias, const float* __restrict__ tb,
    const ushort_t* __restrict__ W1h, const ushort_t* __restrict__ W1l,
    const ushort_t* __restrict__ W2h, const ushort_t* __restrict__ W2l,
    const ushort_t* __restrict__ W3h, const ushort_t* __restrict__ W3l,
    float* __restrict__ hbuf, float* __restrict__ h1a, float* __restrict__ h1b,
    float* __restrict__ out, unsigned* __restrict__ flags)
{
    __shared__ __align__(16) ushort_t Wh[2][96*72];
    __shared__ __align__(16) ushort_t Wl[2][96*72];
    __shared__ __align__(16) ushort_t Ah[2][32*72];
    __shared__ __align__(16) ushort_t Al[2][32*72];
    __shared__ __align__(16) float epi[12*256];

    const int bid = blockIdx.x;
    const int rb  = bid >> 5;
    const int s   = bid & 31;
    const int rowG = rb * 32;
    const int uG   = s * 16;
    const int tid  = threadIdx.x;
    const int wave = tid >> 6;
    const int lane = tid & 63;
    const int quad = lane >> 4;
    const int m    = lane & 15;
    const int wrt  = wave >> 1;              // wave's row-tile (0/1)
    const int g0   = (wave & 1) ? 3 : 0;     // phase-1 gate base
    const int orow = tid >> 3;               // epilogue row 0..31
    const int ou0  = (tid & 7) * 2;          // epilogue u-local base

    // per-thread biases (u-dependent only), loaded once
    float bz[2], brr[2], bhx[2], bhr[2], bl[2], bl2[2];
    float b2z[2], b2r[2], b2h[2], b3z[2], b3r[2], b3h[2];
#pragma unroll
    for (int j = 0; j < 2; ++j){
        int u = uG + ou0 + j;
        bz[j]  = bias[u]        + bias[2560 + u];
        brr[j] = bias[512 + u]  + bias[2560 + 512 + u];
        bhx[j] = bias[1024 + u];
        bhr[j] = bias[2560 + 1024 + u];
        bl[j]  = bias[1536 + u] + bias[2560 + 1536 + u];
        bl2[j] = bias[2048 + u];
        b2z[j] = tb[u];        b2r[j] = tb[512 + u];        b2h[j] = tb[1024 + u];
        b3z[j] = tb[1536 + u]; b3r[j] = tb[1536 + 512 + u]; b3h[j] = tb[1536 + 1024 + u];
    }
    // register-carried per-(row,u) state
    float h_r[2], l_r[2], t2_r[2], h1a_r[2], h1b_r[2];
#pragma unroll
    for (int j = 0; j < 2; ++j)
        h_r[j] = h0[(size_t)(rowG+orow)*UU + uG + ou0 + j];

    int bno = 0;
    const int abase = (wrt*16 + m)*72 + quad*8;
    const int r16 = quad*4;

    for (int t = 0; t < TT; ++t){
        // ================= phase 1: all 6 gate pre-activations =================
        {
            const float* H = (t == 0) ? h0 : hbuf;
            f32x4 a0 = {0.f,0.f,0.f,0.f}, a1 = {0.f,0.f,0.f,0.f}, a2 = {0.f,0.f,0.f,0.f};
            stage_w(W1h + (size_t)s*96*72, W1l + (size_t)s*96*72, Wh[0], Wl[0], 864, tid);
            stage_a1(H, x, rowG, 0, t, Ah[0], Al[0], tid);
            __syncthreads();
            for (int kc = 0; kc < 12; ++kc){
                int cur = kc & 1;
                if (kc < 11){
                    size_t wo = ((size_t)(kc+1)*32 + s)*96*72;
                    stage_w(W1h + wo, W1l + wo, Wh[cur^1], Wl[cur^1], 864, tid);
                    stage_a1(H, x, rowG, kc+1, t, Ah[cur^1], Al[cur^1], tid);
                }
                bf16x8 ah0 = *(const bf16x8*)&Ah[cur][abase];
                bf16x8 ah1 = *(const bf16x8*)&Ah[cur][abase+32];
                bf16x8 al0 = *(const bf16x8*)&Al[cur][abase];
                bf16x8 al1 = *(const bf16x8*)&Al[cur][abase+32];
                int w0 = ((g0+0)*16 + m)*72 + quad*8;
                int w1 = ((g0+1)*16 + m)*72 + quad*8;
                int w2 = ((g0+2)*16 + m)*72 + quad*8;
                a0 = mfma3(ah0, al0, *(const bf16x8*)&Wh[cur][w0],    *(const bf16x8*)&Wl[cur][w0],    a0);
                a0 = mfma3(ah1, al1, *(const bf16x8*)&Wh[cur][w0+32], *(const bf16x8*)&Wl[cur][w0+32], a0);
                a1 = mfma3(ah0, al0, *(const bf16x8*)&Wh[cur][w1],    *(const bf16x8*)&Wl[cur][w1],    a1);
                a1 = mfma3(ah1, al1, *(const bf16x8*)&Wh[cur][w1+32], *(const bf16x8*)&Wl[cur][w1+32], a1);
                a2 = mfma3(ah0, al0, *(const bf16x8*)&Wh[cur][w2],    *(const bf16x8*)&Wl[cur][w2],    a2);
                a2 = mfma3(ah1, al1, *(const bf16x8*)&Wh[cur][w2+32], *(const bf16x8*)&Wl[cur][w2+32], a2);
                __syncthreads();
            }
            float* e0 = &epi[(wrt*6 + g0+0)*256];
            float* e1 = &epi[(wrt*6 + g0+1)*256];
            float* e2 = &epi[(wrt*6 + g0+2)*256];
            e0[(r16+0)*16+m]=a0.x; e0[(r16+1)*16+m]=a0.y; e0[(r16+2)*16+m]=a0.z; e0[(r16+3)*16+m]=a0.w;
            e1[(r16+0)*16+m]=a1.x; e1[(r16+1)*16+m]=a1.y; e1[(r16+2)*16+m]=a1.z; e1[(r16+3)*16+m]=a1.w;
            e2[(r16+0)*16+m]=a2.x; e2[(r16+1)*16+m]=a2.y; e2[(r16+2)*16+m]=a2.z; e2[(r16+3)*16+m]=a2.w;
            __syncthreads();
            int ort = orow >> 4, rr = orow & 15;
#pragma unroll
            for (int j = 0; j < 2; ++j){
                int ul = ou0 + j;
                float cz  = epi[(ort*6+0)*256 + rr*16 + ul];
                float crr = epi[(ort*6+1)*256 + rr*16 + ul];
                float chx = epi[(ort*6+2)*256 + rr*16 + ul];
                float chr = epi[(ort*6+3)*256 + rr*16 + ul];
                float cl  = epi[(ort*6+4)*256 + rr*16 + ul];
                float cl2 = epi[(ort*6+5)*256 + rr*16 + ul];
                float z  = hsig(cz + bz[j]);
                float r_ = hsig(crr + brr[j]);
                float hh = tanhf(chx + bhx[j] + r_*(chr + bhr[j]));
                float h1 = z*h_r[j] + (1.f - z)*hh;
                l_r[j]   = hsig(cl + bl[j]);
                t2_r[j]  = tanhf(cl2 + bl2[j]);
                h1a_r[j] = h1;
                h1a[(size_t)(rowG+orow)*UU + uG + ul] = h1;
            }
        }
        ++bno; gbar(flags, bid, bno);

        // ================= phase 2: transition 0 =================
        {
            f32x4 a0 = {0.f,0.f,0.f,0.f}, a1 = {0.f,0.f,0.f,0.f};
            stage_w(W2h + (size_t)s*48*72, W2l + (size_t)s*48*72, Wh[0], Wl[0], 432, tid);
            stage_a(h1a, rowG, 0, Ah[0], Al[0], tid);
            __syncthreads();
            for (int kc = 0; kc < 8; ++kc){
                int cur = kc & 1;
                if (kc < 7){
                    size_t wo = ((size_t)(kc+1)*32 + s)*48*72;
                    stage_w(W2h + wo, W2l + wo, Wh[cur^1], Wl[cur^1], 432, tid);
                    stage_a(h1a, rowG, (kc+1)*64, Ah[cur^1], Al[cur^1], tid);
                }
                bf16x8 ah0 = *(const bf16x8*)&Ah[cur][abase];
                bf16x8 ah1 = *(const bf16x8*)&Ah[cur][abase+32];
                bf16x8 al0 = *(const bf16x8*)&Al[cur][abase];
                bf16x8 al1 = *(const bf16x8*)&Al[cur][abase+32];
                if (!(wave & 1)){
                    int w0 = (0*16 + m)*72 + quad*8;
                    int w1 = (1*16 + m)*72 + quad*8;
                    a0 = mfma3(ah0, al0, *(const bf16x8*)&Wh[cur][w0],    *(const bf16x8*)&Wl[cur][w0],    a0);
                    a0 = mfma3(ah1, al1, *(const bf16x8*)&Wh[cur][w0+32], *(const bf16x8*)&Wl[cur][w0+32], a0);
                    a1 = mfma3(ah0, al0, *(const bf16x8*)&Wh[cur][w1],    *(const bf16x8*)&Wl[cur][w1],    a1);
                    a1 = mfma3(ah1, al1, *(const bf16x8*)&Wh[cur][w1+32], *(const bf16x8*)&Wl[cur][w1+32], a1);
                } else {
                    int w2 = (2*16 + m)*72 + quad*8;
                    a0 = mfma3(ah0, al0, *(const bf16x8*)&Wh[cur][w2],    *(const bf16x8*)&Wl[cur][w2],    a0);
                    a0 = mfma3(ah1, al1, *(const bf16x8*)&Wh[cur][w2+32], *(const bf16x8*)&Wl[cur][w2+32], a0);
                }
                __syncthreads();
            }
            if (!(wave & 1)){
                float* e0 = &epi[(wrt*3 + 0)*256];
                float* e1 = &epi[(wrt*3 + 1)*256];
                e0[(r16+0)*16+m]=a0.x; e0[(r16+1)*16+m]=a0.y; e0[(r16+2)*16+m]=a0.z; e0[(r16+3)*16+m]=a0.w;
                e1[(r16+0)*16+m]=a1.x; e1[(r16+1)*16+m]=a1.y; e1[(r16+2)*16+m]=a1.z; e1[(r16+3)*16+m]=a1.w;
            } else {
                float* e2 = &epi[(wrt*3 + 2)*256];
                e2[(r16+0)*16+m]=a0.x; e2[(r16+1)*16+m]=a0.y; e2[(r16+2)*16+m]=a0.z; e2[(r16+3)*16+m]=a0.w;
            }
            __syncthreads();
            int ort = orow >> 4, rr = orow & 15;
#pragma unroll
            for (int j = 0; j < 2; ++j){
                int ul = ou0 + j;
                float c0 = epi[(ort*3+0)*256 + rr*16 + ul];
                float c1 = epi[(ort*3+1)*256 + rr*16 + ul];
                float c2 = epi[(ort*3+2)*256 + rr*16 + ul];
                float zt = hsig(c0 + b2z[j]);
                float rt = hsig(c1 + b2r[j]);
                float ht = tanhf(rt*(c2 + b2h[j]));
                float v  = zt*h1a_r[j] + (1.f - zt)*ht;
                h1b_r[j] = v;
                h1b[(size_t)(rowG+orow)*UU + uG + ul] = v;
            }
        }
        ++bno; gbar(flags, bid, bno);

        // ================= phase 3: transition 1 + output gate =================
        {
            f32x4 a0 = {0.f,0.f,0.f,0.f}, a1 = {0.f,0.f,0.f,0.f};
            stage_w(W3h + (size_t)s*48*72, W3l + (size_t)s*48*72, Wh[0], Wl[0], 432, tid);
            stage_a(h1b, rowG, 0, Ah[0], Al[0], tid);
            __syncthreads();
            for (int kc = 0; kc < 8; ++kc){
                int cur = kc & 1;
                if (kc < 7){
                    size_t wo = ((size_t)(kc+1)*32 + s)*48*72;
                    stage_w(W3h + wo, W3l + wo, Wh[cur^1], Wl[cur^1], 432, tid);
                    stage_a(h1b, rowG, (kc+1)*64, Ah[cur^1], Al[cur^1], tid);
                }
                bf16x8 ah0 = *(const bf16x8*)&Ah[cur][abase];
                bf16x8 ah1 = *(const bf16x8*)&Ah[cur][abase+32];
                bf16x8 al0 = *(const bf16x8*)&Al[cur][abase];
                bf16x8 al1 = *(const bf16x8*)&Al[cur][abase+32];
                if (!(wave & 1)){
                    int w0 = (0*16 + m)*72 + quad*8;
                    int w1 = (1*16 + m)*72 + quad*8;
                    a0 = mfma3(ah0, al0, *(const bf16x8*)&Wh[cur][w0],    *(const bf16x8*)&Wl[cur][w0],    a0);
                    a0 = mfma3(ah1, al1, *(const bf16x8*)&Wh[cur][w0+32], *(const bf16x8*)&Wl[cur][w0+32], a0);
                    a1 = mfma3(ah0, al0, *(const bf16x8*)&Wh[cur][w1],    *(const bf16x8*)&Wl[cur][w1],    a1);
                    a1 = mfma3(ah1, al1, *(const bf16x8*)&Wh[cur][w1+32], *(const bf16x8*)&Wl[cur][w1+32], a1);
                } else {
                    int w2 = (2*16 + m)*72 + quad*8;
                    a0 = mfma3(ah0, al0, *(const bf16x8*)&Wh[cur][w2],    *(const bf16x8*)&Wl[cur][w2],    a0);
                    a0 = mfma3(ah1, al1, *(const bf16x8*)&Wh[cur][w2+32], *(const bf16x8*)&Wl[cur][w2+32], a0);
                }
                __syncthreads();
            }
            if (!(wave & 1)){
                float* e0 = &epi[(wrt*3 + 0)*256];
                float* e1 = &epi[(wrt*3 + 1)*256];
                e0[(r16+0)*16+m]=a0.x; e0[(r16+1)*16+m]=a0.y; e0[(r16+2)*16+m]=a0.z; e0[(r16+3)*16+m]=a0.w;
                e1[(r16+0)*16+m]=a1.x; e1[(r16+1)*16+m]=a1.y; e1[(r16+2)*16+m]=a1.z; e1[(r16+3)*16+m]=a1.w;
            } else {
                float* e2 = &epi[(wrt*3 + 2)*256];
                e2[(r16+0)*16+m]=a0.x; e2[(r16+1)*16+m]=a0.y; e2[(r16+2)*16+m]=a0.z; e2[(r16+3)*16+m]=a0.w;
            }
            __syncthreads();
            int ort = orow >> 4, rr = orow & 15;
#pragma unroll
            for (int j = 0; j < 2; ++j){
                int ul = ou0 + j;
                float c0 = epi[(ort*3+0)*256 + rr*16 + ul];
                float c1 = epi[(ort*3+1)*256 + rr*16 + ul];
                float c2 = epi[(ort*3+2)*256 + rr*16 + ul];
                float zt = hsig(c0 + b3z[j]);
                float rt = hsig(c1 + b3r[j]);
                float ht = tanhf(rt*(c2 + b3h[j]));
                float h2 = zt*h1b_r[j] + (1.f - zt)*ht;
                float ho = l_r[j]*h2 + (1.f - l_r[j])*t2_r[j];
                h_r[j] = ho;
                hbuf[(size_t)(rowG+orow)*UU + uG + ul] = ho;
                out[((size_t)(rowG+orow)*TT + t)*UU + uG + ul] = ho;
            }
        }
        ++bno; gbar(flags, bid, bno);
    }
}

extern "C" void kernel_launch(void* const* d_in, const int* in_sizes, int n_in,
                              void* d_out, int out_size, void* d_ws, size_t ws_size,
                              hipStream_t stream) {
    const float* x      = (const float*)d_in[0];
    const float* h0     = (const float*)d_in[1];
    const float* kernel = (const float*)d_in[2];
    const float* rk     = (const float*)d_in[3];
    const float* tk     = (const float*)d_in[4];
    const float* bias   = (const float*)d_in[5];
    const float* tb     = (const float*)d_in[6];
    float* out = (float*)d_out;

    // workspace layout (~19.3 MB)
    ushort_t* W1h = (ushort_t*)d_ws;
    ushort_t* W1l = W1h + W1T_E;
    ushort_t* W2h = W1l + W1T_E;
    ushort_t* W2l = W2h + W2T_E;
    ushort_t* W3h = W2l + W2T_E;
    ushort_t* W3l = W3h + W2T_E;
    float* hbuf = (float*)(W3l + W2T_E);
    float* h1a  = hbuf + (size_t)BB*UU;
    float* h1b  = h1a  + (size_t)BB*UU;
    unsigned* flags = (unsigned*)(h1b + (size_t)BB*UU);

    long pack_elems = (long)W1T_E + 2L*W2T_E + 1024;
    pack_all<<<dim3((unsigned)((pack_elems + 255)/256)), dim3(256), 0, stream>>>(
        kernel, rk, tk, W1h, W1l, W2h, W2l, W3h, W3l, flags);

    void* args[] = {(void*)&x, (void*)&h0, (void*)&bias, (void*)&tb,
                    (void*)&W1h, (void*)&W1l, (void*)&W2h, (void*)&W2l,
                    (void*)&W3h, (void*)&W3l,
                    (void*)&hbuf, (void*)&h1a, (void*)&h1b,
                    (void*)&out, (void*)&flags};
    hipError_t err = hipLaunchCooperativeKernel((void*)scan_kernel, dim3(NBLK),
                                                dim3(256), args, 0, stream);
    if (err != hipSuccess){
        (void)hipGetLastError();
        scan_kernel<<<dim3(NBLK), dim3(256), 0, stream>>>(
            x, h0, bias, tb, W1h, W1l, W2h, W2l, W3h, W3l,
            hbuf, h1a, h1b, out, flags);
    }
}

// Round 6
// 17021.539 us; speedup vs baseline: 1.8344x; 1.0971x over previous
//
#include <hip/hip_runtime.h>
#include <math.h>

#define BB 256
#define TT 128
#define DD 256
#define UU 512
#define NBLK 256

typedef unsigned short ushort_t;
typedef __attribute__((ext_vector_type(8))) short bf16x8;
typedef __attribute__((ext_vector_type(4))) float f32x4;
typedef __attribute__((ext_vector_type(4))) unsigned short us4;

// W1: [kc 12][slab 32][chunk 7168] (6912 = 96 cols x 72 kpad, +256 pad)
// W2/W3: [kc 8][slab 32][chunk 3584] (3456 = 48 cols x 72 kpad, +128 pad)
#define W1C 7168
#define W2C 3584
#define W1_E (12*32*W1C)   // 2,752,512 ushorts
#define W2_E (8*32*W2C)    //   917,504 ushorts

__device__ __forceinline__ float hsig(float x){ return fminf(fmaxf(0.2f*x+0.5f,0.f),1.f); }
__device__ __forceinline__ ushort_t f2bf(float f){
    unsigned u = __float_as_uint(f);
    u = u + 0x7fffu + ((u>>16)&1u);        // RNE
    return (ushort_t)(u>>16);
}
__device__ __forceinline__ float bf2f(ushort_t h){ return __uint_as_float(((unsigned)h)<<16); }

// A split hi/lo vs single-bf16 W: D += (Ah + Al) * W  (~full fp32 A precision)
__device__ __forceinline__ f32x4 mfma2(bf16x8 ah, bf16x8 al, bf16x8 w, f32x4 c){
    c = __builtin_amdgcn_mfma_f32_16x16x32_bf16(ah, w, c, 0, 0, 0);
    c = __builtin_amdgcn_mfma_f32_16x16x32_bf16(al, w, c, 0, 0, 0);
    return c;
}

// async global->LDS: per-lane gsrc (16B each), wave-uniform LDS dst; HW adds lane*16
__device__ __forceinline__ void glds16(const ushort_t* g, ushort_t* l){
    __builtin_amdgcn_global_load_lds(
        (const __attribute__((address_space(1))) void*)g,
        (__attribute__((address_space(3))) void*)l, 16, 0, 0);
}

// ---------------------------------------------------------------------------
// One-time pack: single-bf16 gate-interleaved weights in glds-linear chunks.
// Gate order W1 g: 0=z 1=r 2=hx 3=hr 4=l 5=l2; W2/3 g: 0=z 1=r 2=h.
// ---------------------------------------------------------------------------
__global__ __launch_bounds__(256) void pack_all(
    const float* __restrict__ kernel_, const float* __restrict__ rk,
    const float* __restrict__ tk,
    ushort_t* __restrict__ W1, ushort_t* __restrict__ W2, ushort_t* __restrict__ W3,
    unsigned* __restrict__ flags)
{
    long idx = (long)blockIdx.x*256 + threadIdx.x;
    if (idx < W1_E){
        int slot = (int)(idx % W1C); int chunk = (int)(idx / W1C);
        int s = chunk & 31, kc = chunk >> 5;
        float v = 0.f;
        if (slot < 6912){
            int col = slot / 72, kk = slot % 72;
            int g = col >> 4, u = s*16 + (col & 15);
            int k = kc*64 + kk;
            if (kk < 64){
                if (k < UU){
                    if (g==0)      v = rk[(size_t)k*2048 + u];
                    else if (g==1) v = rk[(size_t)k*2048 + 512 + u];
                    else if (g==3) v = rk[(size_t)k*2048 + 1024 + u];
                    else if (g==4) v = rk[(size_t)k*2048 + 1536 + u];
                } else {
                    int k2 = k - UU;
                    if (g==0)      v = kernel_[(size_t)k2*2560 + u];
                    else if (g==1) v = kernel_[(size_t)k2*2560 + 512 + u];
                    else if (g==2) v = kernel_[(size_t)k2*2560 + 1024 + u];
                    else if (g==4) v = kernel_[(size_t)k2*2560 + 1536 + u];
                    else if (g==5) v = kernel_[(size_t)k2*2560 + 2048 + u];
                }
            }
        }
        W1[idx] = f2bf(v);
        return;
    }
    idx -= W1_E;
    if (idx < 2L*W2_E){
        int layer = (int)(idx / W2_E);
        long j = idx % W2_E;
        int slot = (int)(j % W2C); int chunk = (int)(j / W2C);
        int s = chunk & 31, kc = chunk >> 5;
        float v = 0.f;
        if (slot < 3456){
            int col = slot / 72, kk = slot % 72;
            int g = col >> 4, u = s*16 + (col & 15);
            int k = kc*64 + kk;
            if (kk < 64) v = tk[((size_t)layer*UU + k)*1536 + g*512 + u];
        }
        (layer ? W3 : W2)[j] = f2bf(v);
        return;
    }
    idx -= 2L*W2_E;
    if (idx < 1024) flags[idx] = 0u;
}

// ---------------------------------------------------------------------------
// Two-level grid barrier (cumulative counts). flags: [g*32] group ctrs |
// [256] root | [512+g*32] release mirrors | [960] broken.
// ---------------------------------------------------------------------------
__device__ __forceinline__ void gbar(unsigned* flags, int bid, int bno){
    __syncthreads();
    if (threadIdx.x == 0){
        unsigned grp = (unsigned)(bid & 7);
        __threadfence();
        if (__hip_atomic_load(&flags[960], __ATOMIC_RELAXED, __HIP_MEMORY_SCOPE_AGENT) == 0u){
            unsigned prev = __hip_atomic_fetch_add(&flags[grp*32], 1u,
                                __ATOMIC_ACQ_REL, __HIP_MEMORY_SCOPE_AGENT);
            if (prev == (unsigned)(bno*32 - 1)){
                unsigned pr = __hip_atomic_fetch_add(&flags[256], 1u,
                                __ATOMIC_ACQ_REL, __HIP_MEMORY_SCOPE_AGENT);
                if (pr == (unsigned)(bno*8 - 1)){
                    for (int g2 = 0; g2 < 8; ++g2)
                        __hip_atomic_store(&flags[512 + g2*32], (unsigned)bno,
                                __ATOMIC_RELEASE, __HIP_MEMORY_SCOPE_AGENT);
                }
            }
            long spins = 0;
            while (__hip_atomic_load(&flags[512 + grp*32], __ATOMIC_ACQUIRE,
                                     __HIP_MEMORY_SCOPE_AGENT) < (unsigned)bno){
                __builtin_amdgcn_s_sleep(1);
                if (++spins > 2000000L){
                    __hip_atomic_store(&flags[960], 1u, __ATOMIC_RELEASE,
                                       __HIP_MEMORY_SCOPE_AGENT);
                    break;
                }
            }
        }
    }
    __syncthreads();
}

// convert 2 float4 -> bf16 hi/lo, write to [row][72] LDS image
__device__ __forceinline__ void a_write(float4 v0, float4 v1, int i0,
                                        ushort_t* ah, ushort_t* al){
#pragma unroll
    for (int it = 0; it < 2; ++it){
        float4 v = it ? v1 : v0;
        int i = i0 + it*256;
        int row = i >> 4, kq = (i & 15) * 4;
        ushort_t h0_ = f2bf(v.x), h1_ = f2bf(v.y), h2_ = f2bf(v.z), h3_ = f2bf(v.w);
        us4 hv = {h0_, h1_, h2_, h3_};
        us4 lv = {f2bf(v.x - bf2f(h0_)), f2bf(v.y - bf2f(h1_)),
                  f2bf(v.z - bf2f(h2_)), f2bf(v.w - bf2f(h3_))};
        *(us4*)&ah[row*72 + kq] = hv;
        *(us4*)&al[row*72 + kq] = lv;
    }
}

__device__ __forceinline__ void a_load(const float* __restrict__ A, int rowG,
                                       int kbase, int tid, float4& v0, float4& v1){
    int i = tid;
    v0 = *(const float4*)(A + (size_t)(rowG + (i>>4))*UU + kbase + (i&15)*4);
    i = tid + 256;
    v1 = *(const float4*)(A + (size_t)(rowG + (i>>4))*UU + kbase + (i&15)*4);
}

// phase-1 A: kc<8 from H, kc>=8 from x[:,t,:]
__device__ __forceinline__ void a_load1(const float* __restrict__ H,
                                        const float* __restrict__ x, int rowG,
                                        int kc, int t, int tid, float4& v0, float4& v1){
#pragma unroll
    for (int it = 0; it < 2; ++it){
        int i = tid + it*256;
        int row = i >> 4, kq = (i & 15) * 4;
        const float* src = (kc < 8)
            ? H + (size_t)(rowG+row)*UU + kc*64 + kq
            : x + ((size_t)(rowG+row)*TT + t)*DD + (kc-8)*64 + kq;
        if (it) v1 = *(const float4*)src; else v0 = *(const float4*)src;
    }
}

// ---------------------------------------------------------------------------
// Persistent MFMA scan. 256 blocks = 8 row-blocks(32) x 32 u-slabs(16).
// ---------------------------------------------------------------------------
__global__ __launch_bounds__(256) void scan_kernel(
    const float* __restrict__ x, const float* __restrict__ h0,
    const float* __restrict__ bias, const float* __restrict__ tb,
    const ushort_t* __restrict__ W1, const ushort_t* __restrict__ W2,
    const ushort_t* __restrict__ W3,
    float* __restrict__ hbuf, float* __restrict__ h1a, float* __restrict__ h1b,
    float* __restrict__ out, unsigned* __restrict__ flags)
{
    __shared__ __align__(16) ushort_t Wb[2][W1C];       // 28.7 KB
    __shared__ __align__(16) ushort_t Ah[2][32*72];     // 9.2 KB
    __shared__ __align__(16) ushort_t Al[2][32*72];     // 9.2 KB
    __shared__ __align__(16) float epi[12*256];         // 12.3 KB

    const int bid = blockIdx.x;
    const int rb  = bid >> 5;
    const int s   = bid & 31;
    const int rowG = rb * 32;
    const int uG   = s * 16;
    const int tid  = threadIdx.x;
    const int wave = tid >> 6;
    const int lane = tid & 63;
    const int quad = lane >> 4;
    const int m    = lane & 15;
    const int wrt  = wave >> 1;
    const int g0   = (wave & 1) ? 3 : 0;
    const int orow = tid >> 3;
    const int ou0  = (tid & 7) * 2;

    float bz[2], brr[2], bhx[2], bhr[2], bl[2], bl2[2];
    float b2z[2], b2r[2], b2h[2], b3z[2], b3r[2], b3h[2];
#pragma unroll
    for (int j = 0; j < 2; ++j){
        int u = uG + ou0 + j;
        bz[j]  = bias[u]        + bias[2560 + u];
        brr[j] = bias[512 + u]  + bias[2560 + 512 + u];
        bhx[j] = bias[1024 + u];
        bhr[j] = bias[2560 + 1024 + u];
        bl[j]  = bias[1536 + u] + bias[2560 + 1536 + u];
        bl2[j] = bias[2048 + u];
        b2z[j] = tb[u];        b2r[j] = tb[512 + u];        b2h[j] = tb[1024 + u];
        b3z[j] = tb[1536 + u]; b3r[j] = tb[1536 + 512 + u]; b3h[j] = tb[1536 + 1024 + u];
    }
    float h_r[2], l_r[2], t2_r[2], h1a_r[2], h1b_r[2];
#pragma unroll
    for (int j = 0; j < 2; ++j)
        h_r[j] = h0[(size_t)(rowG+orow)*UU + uG + ou0 + j];

    int bno = 0;
    const int abase = (wrt*16 + m)*72 + quad*8;
    const int r16 = quad*4;

    for (int t = 0; t < TT; ++t){
        // ============ phase 1: all 6 gate pre-activations (K=768) ============
        {
            const float* H = (t == 0) ? h0 : hbuf;
            f32x4 a0 = {0,0,0,0}, a1 = {0,0,0,0}, a2 = {0,0,0,0};
            // preload chunk 0
            {
                const ushort_t* wc0 = W1 + (size_t)s*W1C;
                for (int sg = wave; sg < 14; sg += 4)
                    glds16(wc0 + sg*512 + lane*8, &Wb[0][sg*512]);
                float4 v0, v1; a_load1(H, x, rowG, 0, t, tid, v0, v1);
                a_write(v0, v1, tid, Ah[0], Al[0]);
            }
            __syncthreads();
            for (int kc = 0; kc < 12; ++kc){
                int cur = kc & 1;
                float4 v0, v1;
                if (kc < 11){
                    const ushort_t* wcn = W1 + ((size_t)(kc+1)*32 + s)*W1C;
                    for (int sg = wave; sg < 14; sg += 4)
                        glds16(wcn + sg*512 + lane*8, &Wb[cur^1][sg*512]);
                    a_load1(H, x, rowG, kc+1, t, tid, v0, v1);
                }
                bf16x8 ah0 = *(const bf16x8*)&Ah[cur][abase];
                bf16x8 ah1 = *(const bf16x8*)&Ah[cur][abase+32];
                bf16x8 al0 = *(const bf16x8*)&Al[cur][abase];
                bf16x8 al1 = *(const bf16x8*)&Al[cur][abase+32];
                int w0 = ((g0+0)*16 + m)*72 + quad*8;
                int w1 = ((g0+1)*16 + m)*72 + quad*8;
                int w2 = ((g0+2)*16 + m)*72 + quad*8;
                a0 = mfma2(ah0, al0, *(const bf16x8*)&Wb[cur][w0],    a0);
                a0 = mfma2(ah1, al1, *(const bf16x8*)&Wb[cur][w0+32], a0);
                a1 = mfma2(ah0, al0, *(const bf16x8*)&Wb[cur][w1],    a1);
                a1 = mfma2(ah1, al1, *(const bf16x8*)&Wb[cur][w1+32], a1);
                a2 = mfma2(ah0, al0, *(const bf16x8*)&Wb[cur][w2],    a2);
                a2 = mfma2(ah1, al1, *(const bf16x8*)&Wb[cur][w2+32], a2);
                if (kc < 11) a_write(v0, v1, tid, Ah[cur^1], Al[cur^1]);
                __syncthreads();
            }
            float* e0 = &epi[(wrt*6 + g0+0)*256];
            float* e1 = &epi[(wrt*6 + g0+1)*256];
            float* e2 = &epi[(wrt*6 + g0+2)*256];
            e0[(r16+0)*16+m]=a0.x; e0[(r16+1)*16+m]=a0.y; e0[(r16+2)*16+m]=a0.z; e0[(r16+3)*16+m]=a0.w;
            e1[(r16+0)*16+m]=a1.x; e1[(r16+1)*16+m]=a1.y; e1[(r16+2)*16+m]=a1.z; e1[(r16+3)*16+m]=a1.w;
            e2[(r16+0)*16+m]=a2.x; e2[(r16+1)*16+m]=a2.y; e2[(r16+2)*16+m]=a2.z; e2[(r16+3)*16+m]=a2.w;
            __syncthreads();
            int ort = orow >> 4, rr = orow & 15;
#pragma unroll
            for (int j = 0; j < 2; ++j){
                int ul = ou0 + j;
                float cz  = epi[(ort*6+0)*256 + rr*16 + ul];
                float crr = epi[(ort*6+1)*256 + rr*16 + ul];
                float chx = epi[(ort*6+2)*256 + rr*16 + ul];
                float chr = epi[(ort*6+3)*256 + rr*16 + ul];
                float cl  = epi[(ort*6+4)*256 + rr*16 + ul];
                float cl2 = epi[(ort*6+5)*256 + rr*16 + ul];
                float z  = hsig(cz + bz[j]);
                float r_ = hsig(crr + brr[j]);
                float hh = tanhf(chx + bhx[j] + r_*(chr + bhr[j]));
                float h1 = z*h_r[j] + (1.f - z)*hh;
                l_r[j]   = hsig(cl + bl[j]);
                t2_r[j]  = tanhf(cl2 + bl2[j]);
                h1a_r[j] = h1;
                h1a[(size_t)(rowG+orow)*UU + uG + ul] = h1;
            }
        }
        ++bno; gbar(flags, bid, bno);

        // ============ phases 2 & 3: transitions (K=512 each) ============
#pragma unroll 1
        for (int ph = 0; ph < 2; ++ph){
            const float* Ain = ph ? h1b : h1a;
            const ushort_t* Wt = ph ? W3 : W2;
            f32x4 a0 = {0,0,0,0}, a1 = {0,0,0,0};
            {
                const ushort_t* wc0 = Wt + (size_t)s*W2C;
                for (int sg = wave; sg < 7; sg += 4)
                    glds16(wc0 + sg*512 + lane*8, &Wb[0][sg*512]);
                float4 v0, v1; a_load(Ain, rowG, 0, tid, v0, v1);
                a_write(v0, v1, tid, Ah[0], Al[0]);
            }
            __syncthreads();
            for (int kc = 0; kc < 8; ++kc){
                int cur = kc & 1;
                float4 v0, v1;
                if (kc < 7){
                    const ushort_t* wcn = Wt + ((size_t)(kc+1)*32 + s)*W2C;
                    for (int sg = wave; sg < 7; sg += 4)
                        glds16(wcn + sg*512 + lane*8, &Wb[cur^1][sg*512]);
                    a_load(Ain, rowG, (kc+1)*64, tid, v0, v1);
                }
                bf16x8 ah0 = *(const bf16x8*)&Ah[cur][abase];
                bf16x8 ah1 = *(const bf16x8*)&Ah[cur][abase+32];
                bf16x8 al0 = *(const bf16x8*)&Al[cur][abase];
                bf16x8 al1 = *(const bf16x8*)&Al[cur][abase+32];
                if (!(wave & 1)){
                    int w0 = (0*16 + m)*72 + quad*8;
                    int w1 = (1*16 + m)*72 + quad*8;
                    a0 = mfma2(ah0, al0, *(const bf16x8*)&Wb[cur][w0],    a0);
                    a0 = mfma2(ah1, al1, *(const bf16x8*)&Wb[cur][w0+32], a0);
                    a1 = mfma2(ah0, al0, *(const bf16x8*)&Wb[cur][w1],    a1);
                    a1 = mfma2(ah1, al1, *(const bf16x8*)&Wb[cur][w1+32], a1);
                } else {
                    int w2 = (2*16 + m)*72 + quad*8;
                    a0 = mfma2(ah0, al0, *(const bf16x8*)&Wb[cur][w2],    a0);
                    a0 = mfma2(ah1, al1, *(const bf16x8*)&Wb[cur][w2+32], a0);
                }
                if (kc < 7) a_write(v0, v1, tid, Ah[cur^1], Al[cur^1]);
                __syncthreads();
            }
            if (!(wave & 1)){
                float* e0 = &epi[(wrt*3 + 0)*256];
                float* e1 = &epi[(wrt*3 + 1)*256];
                e0[(r16+0)*16+m]=a0.x; e0[(r16+1)*16+m]=a0.y; e0[(r16+2)*16+m]=a0.z; e0[(r16+3)*16+m]=a0.w;
                e1[(r16+0)*16+m]=a1.x; e1[(r16+1)*16+m]=a1.y; e1[(r16+2)*16+m]=a1.z; e1[(r16+3)*16+m]=a1.w;
            } else {
                float* e2 = &epi[(wrt*3 + 2)*256];
                e2[(r16+0)*16+m]=a0.x; e2[(r16+1)*16+m]=a0.y; e2[(r16+2)*16+m]=a0.z; e2[(r16+3)*16+m]=a0.w;
            }
            __syncthreads();
            int ort = orow >> 4, rr = orow & 15;
            if (ph == 0){
#pragma unroll
                for (int j = 0; j < 2; ++j){
                    int ul = ou0 + j;
                    float c0 = epi[(ort*3+0)*256 + rr*16 + ul];
                    float c1 = epi[(ort*3+1)*256 + rr*16 + ul];
                    float c2 = epi[(ort*3+2)*256 + rr*16 + ul];
                    float zt = hsig(c0 + b2z[j]);
                    float rt = hsig(c1 + b2r[j]);
                    float ht = tanhf(rt*(c2 + b2h[j]));
                    float v  = zt*h1a_r[j] + (1.f - zt)*ht;
                    h1b_r[j] = v;
                    h1b[(size_t)(rowG+orow)*UU + uG + ul] = v;
                }
            } else {
#pragma unroll
                for (int j = 0; j < 2; ++j){
                    int ul = ou0 + j;
                    float c0 = epi[(ort*3+0)*256 + rr*16 + ul];
                    float c1 = epi[(ort*3+1)*256 + rr*16 + ul];
                    float c2 = epi[(ort*3+2)*256 + rr*16 + ul];
                    float zt = hsig(c0 + b3z[j]);
                    float rt = hsig(c1 + b3r[j]);
                    float ht = tanhf(rt*(c2 + b3h[j]));
                    float h2 = zt*h1b_r[j] + (1.f - zt)*ht;
                    float ho = l_r[j]*h2 + (1.f - l_r[j])*t2_r[j];
                    h_r[j] = ho;
                    hbuf[(size_t)(rowG+orow)*UU + uG + ul] = ho;
                    out[((size_t)(rowG+orow)*TT + t)*UU + uG + ul] = ho;
                }
            }
            ++bno; gbar(flags, bid, bno);
        }
    }
}

extern "C" void kernel_launch(void* const* d_in, const int* in_sizes, int n_in,
                              void* d_out, int out_size, void* d_ws, size_t ws_size,
                              hipStream_t stream) {
    const float* x      = (const float*)d_in[0];
    const float* h0     = (const float*)d_in[1];
    const float* kernel = (const float*)d_in[2];
    const float* rk     = (const float*)d_in[3];
    const float* tk     = (const float*)d_in[4];
    const float* bias   = (const float*)d_in[5];
    const float* tb     = (const float*)d_in[6];
    float* out = (float*)d_out;

    ushort_t* W1 = (ushort_t*)d_ws;
    ushort_t* W2 = W1 + W1_E;
    ushort_t* W3 = W2 + W2_E;
    float* hbuf = (float*)(W3 + W2_E);
    float* h1a  = hbuf + (size_t)BB*UU;
    float* h1b  = h1a  + (size_t)BB*UU;
    unsigned* flags = (unsigned*)(h1b + (size_t)BB*UU);

    long pack_elems = (long)W1_E + 2L*W2_E + 1024;
    pack_all<<<dim3((unsigned)((pack_elems + 255)/256)), dim3(256), 0, stream>>>(
        kernel, rk, tk, W1, W2, W3, flags);

    void* args[] = {(void*)&x, (void*)&h0, (void*)&bias, (void*)&tb,
                    (void*)&W1, (void*)&W2, (void*)&W3,
                    (void*)&hbuf, (void*)&h1a, (void*)&h1b,
                    (void*)&out, (void*)&flags};
    hipError_t err = hipLaunchCooperativeKernel((void*)scan_kernel, dim3(NBLK),
                                                dim3(256), args, 0, stream);
    if (err != hipSuccess){
        (void)hipGetLastError();
        scan_kernel<<<dim3(NBLK), dim3(256), 0, stream>>>(
            x, h0, bias, tb, W1, W2, W3, hbuf, h1a, h1b, out, flags);
    }
}